// Round 6
// baseline (335.729 us; speedup 1.0000x reference)
//
#include <hip/hip_runtime.h>

// GNN: 2 x (SimpleConv(mean, cat) -> Linear(256->128) -> ReLU)
// N=50000 nodes, E=640000 edges, H=128.
//
// R1: k_agg latency-bound -> packed (src,att) CSR + LDS stage + x4 unroll.
// R2: k_scan single-block 90us -> 3-phase multi-block scan.
// R3: bf16 hidden pipeline + LDS-free MFMA bf16 GEMM (fp32 accum).
// R4: k_agg one-wave-per-node ushort2 gathers; A = [X | AGG] two-buffer GEMM.
// R5: fuse agg into GEMM (per-wave gather -> LDS A-frags, no agg round-trip);
//     collapse setup kernels; fold scan2 into scan3. 14 -> 7 launches.

#define HDIM 128
#define SCAN_CHUNK 2048   // elements per block in the scan (256 thr x 8)

typedef __bf16 bf16x8 __attribute__((ext_vector_type(8)));
typedef float floatx4 __attribute__((ext_vector_type(4)));

__device__ __forceinline__ unsigned short f2bf(float f) {
    unsigned int u = __float_as_uint(f);
    unsigned int r = (u + 0x7fff + ((u >> 16) & 1)) >> 16;   // RNE
    return (unsigned short)r;
}
__device__ __forceinline__ float bf2f(unsigned short b) {
    return __uint_as_float((unsigned int)b << 16);
}

// ---- fused setup: [0] edge-dtype detect | zero deg/cursor | cast data->bf16
//      | prepW1 | prepW2 (all independent; branch on blockIdx range) ----
__global__ __launch_bounds__(256) void k_setup(const int* __restrict__ edge, int nwords,
                                               int* __restrict__ flag,
                                               int* __restrict__ degcur, int ndc,
                                               const float* __restrict__ data,
                                               unsigned short* __restrict__ data_bf, int n4,
                                               const float* __restrict__ w1,
                                               unsigned short* __restrict__ w1t,
                                               const float* __restrict__ w2,
                                               unsigned short* __restrict__ w2t,
                                               int zb, int cb) {
    int b = blockIdx.x;
    int t = threadIdx.x;
    if (b == 0) {
        // int64 edges (values < 2^31) -> every odd 32-bit word is 0.
        __shared__ int s_or;
        if (t == 0) s_or = 0;
        __syncthreads();
        int i = t * 2 + 1;
        int v = (i < nwords) ? edge[i] : 0;
        if (v != 0) atomicOr(&s_or, 1);
        __syncthreads();
        if (t == 0) flag[0] = (s_or == 0) ? 1 : 0;  // shift: 1 => int64, 0 => int32
        return;
    }
    b -= 1;
    if (b < zb) {
        int i = b * 256 + t;
        if (i < ndc) degcur[i] = 0;
        return;
    }
    b -= zb;
    if (b < cb) {
        int i = b * 256 + t;
        if (i < n4) {
            float4 v = ((const float4*)data)[i];
            ushort4 o;
            o.x = f2bf(v.x); o.y = f2bf(v.y); o.z = f2bf(v.z); o.w = f2bf(v.w);
            ((ushort4*)data_bf)[i] = o;
        }
        return;
    }
    b -= cb;
    {
        const float* w = (b < 128) ? w1 : w2;
        unsigned short* wt = (b < 128) ? w1t : w2t;
        int bb = (b < 128) ? b : b - 128;
        int idx = bb * 256 + t;          // 0..32767
        int k = idx >> 7;                // 0..255
        int n = idx & 127;               // 0..127
        wt[(size_t)n * 256 + k] = f2bf(w[(size_t)k * 128 + n]);
    }
}

__global__ void k_count(const int* __restrict__ edge, int E, const int* __restrict__ flag,
                        int* __restrict__ deg) {
    int sh = flag[0];
    int i = blockIdx.x * blockDim.x + threadIdx.x;
    if (i < E) {
        int d = edge[(size_t)(E + i) << sh];
        atomicAdd(&deg[d], 1);
    }
}

// ---- scan phase 1: per-block sums ----
__global__ __launch_bounds__(256) void k_scan1(const int* __restrict__ deg, int N,
                                               int* __restrict__ partial) {
    __shared__ int sm[256];
    int t = threadIdx.x;
    int base = blockIdx.x * SCAN_CHUNK + t * 8;
    int s = 0;
#pragma unroll
    for (int j = 0; j < 8; ++j) {
        int i = base + j;
        if (i < N) s += deg[i];
    }
    sm[t] = s;
    __syncthreads();
    for (int st = 128; st > 0; st >>= 1) {
        if (t < st) sm[t] += sm[t + st];
        __syncthreads();
    }
    if (t == 0) partial[blockIdx.x] = sm[0];
}

// ---- scan phase 2 (fused): each block scans the raw partials itself ----
__global__ __launch_bounds__(256) void k_scan3(const int* __restrict__ deg, int N,
                                               const int* __restrict__ partial, int nb,
                                               int* __restrict__ off) {
    __shared__ int sm[256];
    int t = threadIdx.x;
    int b = blockIdx.x;
    int basep = 0;
    for (int i = 0; i < nb; ++i) {
        int v = partial[i];
        if (i < b) basep += v;
    }
    int base = b * SCAN_CHUNK + t * 8;
    int v[8];
    int s = 0;
#pragma unroll
    for (int j = 0; j < 8; ++j) {
        int i = base + j;
        v[j] = (i < N) ? deg[i] : 0;
        s += v[j];
    }
    sm[t] = s;
    __syncthreads();
    for (int st = 1; st < 256; st <<= 1) {
        int tv = (t >= st) ? sm[t - st] : 0;
        __syncthreads();
        sm[t] += tv;
        __syncthreads();
    }
    int run = basep + sm[t] - s;
#pragma unroll
    for (int j = 0; j < 8; ++j) {
        int i = base + j;
        if (i < N) {
            off[i] = run;
            run += v[j];
        }
    }
    if (b == gridDim.x - 1 && t == 255) off[N] = basep + sm[255];
}

// Bucket edges into CSR slots, writing packed {src, att} pairs directly.
__global__ void k_fill(const int* __restrict__ edge, int E, const int* __restrict__ flag,
                       const float* __restrict__ att,
                       const int* __restrict__ off, int* __restrict__ cursor,
                       float2* __restrict__ pse) {
    int sh = flag[0];
    int i = blockIdx.x * blockDim.x + threadIdx.x;
    if (i < E) {
        int s = edge[(size_t)i << sh];        // src
        int d = edge[(size_t)(E + i) << sh];  // dst
        int pos = off[d] + atomicAdd(&cursor[d], 1);
        pse[pos] = make_float2(__int_as_float(s), att[i]);
    }
}

// Fused layer: out[M,128] = relu( [X | AGG(X)][M,256]bf16 @ W + b ).
// Block = 4 waves, 64 rows. Phase 1: wave w computes agg for its 16 nodes
// (edge records are wave-uniform broadcast loads; 4B/lane row gathers),
// writes bf16 results into its private LDS slice in MFMA A-frag order.
// Phase 2: MFMA 16x16x32; A-frags: k<128 from X (global), k>=128 from LDS.
// C/D: col=lane&15, row=quad*4+reg.
__global__ __launch_bounds__(256) void k_layer(const unsigned short* __restrict__ X,
                                               const float2* __restrict__ pse,
                                               const int* __restrict__ off,
                                               const unsigned short* __restrict__ Wt,
                                               const float* __restrict__ bias,
                                               float* __restrict__ outF,
                                               unsigned short* __restrict__ outB,
                                               int M) {
    // sA[wave][kcL][quad][m][j]: 16B-contiguous A-fragments, 4KB per wave.
    __shared__ __align__(16) unsigned short sA[4][4][4][16][8];

    int tid = threadIdx.x;
    int wave = tid >> 6;
    int lane = tid & 63;
    int l16 = lane & 15;
    int quad = lane >> 4;

    // ---- Phase 1: aggregate 16 nodes for this wave ----
    int kcL = lane >> 4;            // for this lane's 2 output columns c0=2*lane
    int qp = (lane & 15) >> 2;
    int j0 = (lane & 3) * 2;
    for (int i = 0; i < 16; ++i) {
        int n = blockIdx.x * 64 + wave * 16 + i;
        float sx = 0.f, sy = 0.f;
        int deg = 0;
        if (n < M) {
            int o0 = off[n], o1 = off[n + 1];
            deg = o1 - o0;
            int j = 0;
            for (; j + 4 <= deg; j += 4) {
                float2 p0 = pse[o0 + j + 0];
                float2 p1 = pse[o0 + j + 1];
                float2 p2 = pse[o0 + j + 2];
                float2 p3 = pse[o0 + j + 3];
                unsigned int u0 = *(const unsigned int*)(X + (size_t)__float_as_int(p0.x) * HDIM + 2 * lane);
                unsigned int u1 = *(const unsigned int*)(X + (size_t)__float_as_int(p1.x) * HDIM + 2 * lane);
                unsigned int u2 = *(const unsigned int*)(X + (size_t)__float_as_int(p2.x) * HDIM + 2 * lane);
                unsigned int u3 = *(const unsigned int*)(X + (size_t)__float_as_int(p3.x) * HDIM + 2 * lane);
                sx = fmaf(bf2f((unsigned short)(u0 & 0xffff)), p0.y, sx);
                sy = fmaf(bf2f((unsigned short)(u0 >> 16)), p0.y, sy);
                sx = fmaf(bf2f((unsigned short)(u1 & 0xffff)), p1.y, sx);
                sy = fmaf(bf2f((unsigned short)(u1 >> 16)), p1.y, sy);
                sx = fmaf(bf2f((unsigned short)(u2 & 0xffff)), p2.y, sx);
                sy = fmaf(bf2f((unsigned short)(u2 >> 16)), p2.y, sy);
                sx = fmaf(bf2f((unsigned short)(u3 & 0xffff)), p3.y, sx);
                sy = fmaf(bf2f((unsigned short)(u3 >> 16)), p3.y, sy);
            }
            for (; j < deg; ++j) {
                float2 p = pse[o0 + j];
                unsigned int u = *(const unsigned int*)(X + (size_t)__float_as_int(p.x) * HDIM + 2 * lane);
                sx = fmaf(bf2f((unsigned short)(u & 0xffff)), p.y, sx);
                sy = fmaf(bf2f((unsigned short)(u >> 16)), p.y, sy);
            }
        }
        float m = fmaxf((float)deg, 1.0f);
        unsigned int o = (unsigned int)f2bf(sx / m) | ((unsigned int)f2bf(sy / m) << 16);
        *(unsigned int*)&sA[wave][kcL][qp][i][j0] = o;
    }
    __syncthreads();

    // ---- Phase 2: MFMA ----
    int row = blockIdx.x * 64 + wave * 16 + l16;
    int rowA = min(row, M - 1);
    const unsigned short* xrow = X + (size_t)rowA * HDIM + quad * 8;

    floatx4 acc[8];
#pragma unroll
    for (int c = 0; c < 8; ++c) acc[c] = (floatx4){0.f, 0.f, 0.f, 0.f};

#pragma unroll
    for (int kc = 0; kc < 8; ++kc) {
        bf16x8 af = (kc < 4) ? *(const bf16x8*)(xrow + kc * 32)
                             : *(const bf16x8*)&sA[wave][kc - 4][quad][l16][0];
#pragma unroll
        for (int c = 0; c < 8; ++c) {
            const unsigned short* bptr = Wt + (size_t)(c * 16 + l16) * 256 + kc * 32 + quad * 8;
            bf16x8 bfr = *(const bf16x8*)bptr;
            acc[c] = __builtin_amdgcn_mfma_f32_16x16x32_bf16(af, bfr, acc[c], 0, 0, 0);
        }
    }

    int orow0 = blockIdx.x * 64 + wave * 16 + quad * 4;
#pragma unroll
    for (int c = 0; c < 8; ++c) {
        int col = c * 16 + l16;
        float bv = bias[col];
#pragma unroll
        for (int r = 0; r < 4; ++r) {
            int orow = orow0 + r;
            if (orow < M) {
                float v = fmaxf(acc[c][r] + bv, 0.f);
                if (outF) outF[(size_t)orow * 128 + col] = v;
                else outB[(size_t)orow * 128 + col] = f2bf(v);
            }
        }
    }
}

extern "C" void kernel_launch(void* const* d_in, const int* in_sizes, int n_in,
                              void* d_out, int out_size, void* d_ws, size_t ws_size,
                              hipStream_t stream) {
    const float* data = (const float*)d_in[0];
    const int* edge = (const int*)d_in[1];
    const float* att = (const float*)d_in[2];
    const float* w1 = (const float*)d_in[3];
    const float* b1 = (const float*)d_in[4];
    const float* w2 = (const float*)d_in[5];
    const float* b2 = (const float*)d_in[6];

    const int N = in_sizes[0] / HDIM;
    const int E = in_sizes[1] / 2;

    char* ws = (char*)d_ws;
    size_t o = 0;
    auto carve = [&](size_t bytes) -> char* {
        char* r = ws + o;
        o = (o + bytes + 255) & ~(size_t)255;
        return r;
    };
    int* flag = (int*)carve(16);
    int* deg = (int*)carve((size_t)2 * N * 4);  // deg[N] + cursor[N]
    int* cursor = deg + N;
    int* off = (int*)carve((size_t)(N + 1) * 4);
    int* partial = (int*)carve(256 * 4);
    float2* pse = (float2*)carve((size_t)E * 8);             // packed {src, att} CSR
    unsigned short* data_bf = (unsigned short*)carve((size_t)N * 128 * 2);
    unsigned short* w1t = (unsigned short*)carve(256 * 128 * 2);
    unsigned short* w2t = (unsigned short*)carve(256 * 128 * 2);
    unsigned short* out1_bf = (unsigned short*)carve((size_t)N * 128 * 2);
    float* outF = (float*)d_out;

    int nw = 2 * E < 512 ? 2 * E : 512;
    int ndc = 2 * N;
    int zb = (ndc + 255) / 256;
    int n4 = N * 128 / 4;
    int cb = (n4 + 255) / 256;
    int setup_blocks = 1 + zb + cb + 256;
    k_setup<<<setup_blocks, 256, 0, stream>>>(edge, nw, flag, deg, ndc,
                                              data, data_bf, n4, w1, w1t, w2, w2t, zb, cb);

    k_count<<<(E + 255) / 256, 256, 0, stream>>>(edge, E, flag, deg);

    int nb = (N + SCAN_CHUNK - 1) / SCAN_CHUNK;  // 25 for N=50000
    k_scan1<<<nb, 256, 0, stream>>>(deg, N, partial);
    k_scan3<<<nb, 256, 0, stream>>>(deg, N, partial, nb, off);

    k_fill<<<(E + 255) / 256, 256, 0, stream>>>(edge, E, flag, att, off, cursor, pse);

    int gb = (N + 63) / 64;
    k_layer<<<gb, 256, 0, stream>>>(data_bf, pse, off, w1t, b1, nullptr, out1_bf, N);
    k_layer<<<gb, 256, 0, stream>>>(out1_bf, pse, off, w2t, b2, outF, nullptr, N);
}

// Round 7
// 257.951 us; speedup vs baseline: 1.3015x; 1.3015x over previous
//
#include <hip/hip_runtime.h>

// GNN: 2 x (SimpleConv(mean, cat) -> Linear(256->128) -> ReLU)
// N=50000 nodes, E=640000 edges, H=128.
//
// R1: k_agg latency-bound -> packed (src,att) CSR + LDS stage + x4 unroll.
// R2: k_scan single-block 90us -> multi-block scan.
// R3: bf16 hidden pipeline + LDS-free MFMA bf16 GEMM (fp32 accum).
// R4: k_agg one-wave-per-node ushort2 gathers; A = [X | AGG] two-buffer GEMM.
// R5: launch-count reduction (worth ~8.6us/launch).
// R6: k_layer fusion REGRESSED (serial per-wave gather, occ 29%) -> revert.
// R7: padded CSR (cap=48): kills count+scan entirely; detect folded into fill;
//     overflow list for correctness on arbitrary inputs. 6 launches total.

#define HDIM 128
#define CAP 48            // padded CSR capacity; P(deg>48 | Poisson 12.8) ~ 3e-14

typedef __bf16 bf16x8 __attribute__((ext_vector_type(8)));
typedef float floatx4 __attribute__((ext_vector_type(4)));

__device__ __forceinline__ unsigned short f2bf(float f) {
    unsigned int u = __float_as_uint(f);
    unsigned int r = (u + 0x7fff + ((u >> 16) & 1)) >> 16;   // RNE
    return (unsigned short)r;
}
__device__ __forceinline__ float bf2f(unsigned short b) {
    return __uint_as_float((unsigned int)b << 16);
}

// ---- fused setup: zero cursor/ovf | cast data->bf16 | prepW1 | prepW2 ----
__global__ __launch_bounds__(256) void k_setup(int* __restrict__ cursor, int nz,
                                               const float* __restrict__ data,
                                               unsigned short* __restrict__ data_bf, int n4,
                                               const float* __restrict__ w1,
                                               unsigned short* __restrict__ w1t,
                                               const float* __restrict__ w2,
                                               unsigned short* __restrict__ w2t,
                                               int zb, int cb) {
    int b = blockIdx.x;
    int t = threadIdx.x;
    if (b < zb) {
        int i = b * 256 + t;
        if (i < nz) cursor[i] = 0;
        return;
    }
    b -= zb;
    if (b < cb) {
        int i = b * 256 + t;
        if (i < n4) {
            float4 v = ((const float4*)data)[i];
            ushort4 o;
            o.x = f2bf(v.x); o.y = f2bf(v.y); o.z = f2bf(v.z); o.w = f2bf(v.w);
            ((ushort4*)data_bf)[i] = o;
        }
        return;
    }
    b -= cb;
    {
        const float* w = (b < 128) ? w1 : w2;
        unsigned short* wt = (b < 128) ? w1t : w2t;
        int bb = (b < 128) ? b : b - 128;
        int idx = bb * 256 + t;          // 0..32767
        int k = idx >> 7;                // 0..255
        int n = idx & 127;               // 0..127
        wt[(size_t)n * 256 + k] = f2bf(w[(size_t)k * 128 + n]);
    }
}

// Padded-CSR fill: slot = atomicAdd(cursor[dst]); pse[dst*CAP+slot] = {src,att}.
// Per-block redundant int64/int32 detect (odd words all-zero => int64).
// Overflow (slot >= CAP): append {dst,src,att} to ovf list (correctness path).
__global__ __launch_bounds__(256) void k_fill(const int* __restrict__ edge, int E,
                                              const float* __restrict__ att,
                                              int* __restrict__ cursor,
                                              int* __restrict__ ovf_cnt,
                                              float2* __restrict__ pse,
                                              float4* __restrict__ ovf) {
    __shared__ int s_or;
    int t = threadIdx.x;
    if (t == 0) s_or = 0;
    __syncthreads();
    int nw = 2 * E < 512 ? 2 * E : 512;
    int iw = t * 2 + 1;
    int vw = (iw < nw) ? edge[iw] : 0;
    if (vw != 0) atomicOr(&s_or, 1);
    __syncthreads();
    int sh = (s_or == 0) ? 1 : 0;  // 1 => int64 stride, 0 => int32

    int e = blockIdx.x * 256 + t;
    if (e < E) {
        int s = edge[(size_t)e << sh];
        int d = edge[(size_t)(E + e) << sh];
        int slot = atomicAdd(&cursor[d], 1);
        float a = att[e];
        if (slot < CAP) {
            pse[(size_t)d * CAP + slot] = make_float2(__int_as_float(s), a);
        } else {
            int oi = atomicAdd(ovf_cnt, 1);
            ovf[oi] = make_float4(__int_as_float(d), __int_as_float(s), a, 0.f);
        }
    }
}

// One WAVE per node, 2 nodes per 128-thread block. Lane covers 2 columns via
// ushort2 gathers. Single LDS stage covers all slots (deg <= CAP = 48).
__global__ __launch_bounds__(128) void k_agg(const unsigned short* __restrict__ x,
                                             const float2* __restrict__ pse,
                                             const int* __restrict__ cursor,
                                             const int* __restrict__ ovf_cnt,
                                             const float4* __restrict__ ovf,
                                             unsigned short* __restrict__ agg, int N) {
    int wave = threadIdx.x >> 6;
    int lane = threadIdx.x & 63;
    int n = blockIdx.x * 2 + wave;
    bool valid = n < N;
    int deg = valid ? cursor[n] : 0;
    int m = min(deg, CAP);

    __shared__ float2 sp[2][CAP];
    if (lane < m) sp[wave][lane] = pse[(size_t)n * CAP + lane];
    __syncthreads();

    float sx = 0.f, sy = 0.f;
    int j = 0;
    for (; j + 4 <= m; j += 4) {
        float2 p0 = sp[wave][j + 0];
        float2 p1 = sp[wave][j + 1];
        float2 p2 = sp[wave][j + 2];
        float2 p3 = sp[wave][j + 3];
        unsigned int u0 = *(const unsigned int*)(x + (size_t)__float_as_int(p0.x) * HDIM + 2 * lane);
        unsigned int u1 = *(const unsigned int*)(x + (size_t)__float_as_int(p1.x) * HDIM + 2 * lane);
        unsigned int u2 = *(const unsigned int*)(x + (size_t)__float_as_int(p2.x) * HDIM + 2 * lane);
        unsigned int u3 = *(const unsigned int*)(x + (size_t)__float_as_int(p3.x) * HDIM + 2 * lane);
        sx = fmaf(bf2f((unsigned short)(u0 & 0xffff)), p0.y, sx);
        sy = fmaf(bf2f((unsigned short)(u0 >> 16)), p0.y, sy);
        sx = fmaf(bf2f((unsigned short)(u1 & 0xffff)), p1.y, sx);
        sy = fmaf(bf2f((unsigned short)(u1 >> 16)), p1.y, sy);
        sx = fmaf(bf2f((unsigned short)(u2 & 0xffff)), p2.y, sx);
        sy = fmaf(bf2f((unsigned short)(u2 >> 16)), p2.y, sy);
        sx = fmaf(bf2f((unsigned short)(u3 & 0xffff)), p3.y, sx);
        sy = fmaf(bf2f((unsigned short)(u3 >> 16)), p3.y, sy);
    }
    for (; j < m; ++j) {
        float2 p = sp[wave][j];
        unsigned int u = *(const unsigned int*)(x + (size_t)__float_as_int(p.x) * HDIM + 2 * lane);
        sx = fmaf(bf2f((unsigned short)(u & 0xffff)), p.y, sx);
        sy = fmaf(bf2f((unsigned short)(u >> 16)), p.y, sy);
    }

    // Overflow correctness path (normally ovf_cnt == 0 -> skipped).
    int oc = ovf_cnt[0];
    if (oc > 0 && valid) {
        for (int k = 0; k < oc; ++k) {
            float4 f = ovf[k];
            if (__float_as_int(f.x) == n) {
                unsigned int u = *(const unsigned int*)(x + (size_t)__float_as_int(f.y) * HDIM + 2 * lane);
                sx = fmaf(bf2f((unsigned short)(u & 0xffff)), f.z, sx);
                sy = fmaf(bf2f((unsigned short)(u >> 16)), f.z, sy);
            }
        }
    }

    if (valid) {
        float md = fmaxf((float)deg, 1.0f);
        unsigned int o = (unsigned int)f2bf(sx / md) | ((unsigned int)f2bf(sy / md) << 16);
        *(unsigned int*)(agg + (size_t)n * HDIM + 2 * lane) = o;
    }
}

// out[M,128] = relu( [X | AGG][M,256]bf16 @ W[256,128] + b ), MFMA 16x16x32.
// LDS-free: A-frags from X (k<128) / AGG (k>=128); B-frags from Wt[128,256].
// C/D: col=lane&15, row=quad*4+reg. Block = 4 waves, 64 rows/block.
__global__ __launch_bounds__(256) void k_gemm_mfma(const unsigned short* __restrict__ X,
                                                   const unsigned short* __restrict__ AGG,
                                                   const unsigned short* __restrict__ Wt,
                                                   const float* __restrict__ bias,
                                                   float* __restrict__ outF,
                                                   unsigned short* __restrict__ outB,
                                                   int M) {
    int tid = threadIdx.x;
    int wave = tid >> 6;
    int lane = tid & 63;
    int l16 = lane & 15;
    int quad = lane >> 4;

    int row = blockIdx.x * 64 + wave * 16 + l16;
    int rowA = min(row, M - 1);
    const unsigned short* xrow = X + (size_t)rowA * HDIM + quad * 8;
    const unsigned short* arow = AGG + (size_t)rowA * HDIM + quad * 8;

    floatx4 acc[8];
#pragma unroll
    for (int c = 0; c < 8; ++c) acc[c] = (floatx4){0.f, 0.f, 0.f, 0.f};

#pragma unroll
    for (int kc = 0; kc < 8; ++kc) {
        bf16x8 af = (kc < 4) ? *(const bf16x8*)(xrow + kc * 32)
                             : *(const bf16x8*)(arow + (kc - 4) * 32);
#pragma unroll
        for (int c = 0; c < 8; ++c) {
            const unsigned short* bptr = Wt + (size_t)(c * 16 + l16) * 256 + kc * 32 + quad * 8;
            bf16x8 bfr = *(const bf16x8*)bptr;
            acc[c] = __builtin_amdgcn_mfma_f32_16x16x32_bf16(af, bfr, acc[c], 0, 0, 0);
        }
    }

    int orow0 = blockIdx.x * 64 + wave * 16 + quad * 4;
#pragma unroll
    for (int c = 0; c < 8; ++c) {
        int col = c * 16 + l16;
        float bv = bias[col];
#pragma unroll
        for (int r = 0; r < 4; ++r) {
            int orow = orow0 + r;
            if (orow < M) {
                float v = fmaxf(acc[c][r] + bv, 0.f);
                if (outF) outF[(size_t)orow * 128 + col] = v;
                else outB[(size_t)orow * 128 + col] = f2bf(v);
            }
        }
    }
}

extern "C" void kernel_launch(void* const* d_in, const int* in_sizes, int n_in,
                              void* d_out, int out_size, void* d_ws, size_t ws_size,
                              hipStream_t stream) {
    const float* data = (const float*)d_in[0];
    const int* edge = (const int*)d_in[1];
    const float* att = (const float*)d_in[2];
    const float* w1 = (const float*)d_in[3];
    const float* b1 = (const float*)d_in[4];
    const float* w2 = (const float*)d_in[5];
    const float* b2 = (const float*)d_in[6];

    const int N = in_sizes[0] / HDIM;
    const int E = in_sizes[1] / 2;

    char* ws = (char*)d_ws;
    size_t o = 0;
    auto carve = [&](size_t bytes) -> char* {
        char* r = ws + o;
        o = (o + bytes + 255) & ~(size_t)255;
        return r;
    };
    int* cursor = (int*)carve((size_t)(N + 4) * 4);   // cursor[N] + ovf_cnt at [N]
    int* ovf_cnt = cursor + N;
    float2* pse = (float2*)carve((size_t)N * CAP * 8);        // padded CSR {src, att}
    float4* ovf = (float4*)carve((size_t)E * 16);             // overflow (usually empty)
    unsigned short* data_bf = (unsigned short*)carve((size_t)N * 128 * 2);
    unsigned short* w1t = (unsigned short*)carve(256 * 128 * 2);
    unsigned short* w2t = (unsigned short*)carve(256 * 128 * 2);
    unsigned short* agg_bf = (unsigned short*)carve((size_t)N * 128 * 2);
    unsigned short* out1_bf = (unsigned short*)carve((size_t)N * 128 * 2);
    float* outF = (float*)d_out;

    int nz = N + 4;
    int zb = (nz + 255) / 256;
    int n4 = N * 128 / 4;
    int cb = (n4 + 255) / 256;
    k_setup<<<zb + cb + 256, 256, 0, stream>>>(cursor, nz, data, data_bf, n4,
                                               w1, w1t, w2, w2t, zb, cb);

    k_fill<<<(E + 255) / 256, 256, 0, stream>>>(edge, E, att, cursor, ovf_cnt, pse, ovf);

    int ga = (N + 1) / 2;
    int gb = (N + 63) / 64;
    // Layer 1
    k_agg<<<ga, 128, 0, stream>>>(data_bf, pse, cursor, ovf_cnt, ovf, agg_bf, N);
    k_gemm_mfma<<<gb, 256, 0, stream>>>(data_bf, agg_bf, w1t, b1, nullptr, out1_bf, N);
    // Layer 2
    k_agg<<<ga, 128, 0, stream>>>(out1_bf, pse, cursor, ovf_cnt, ovf, agg_bf, N);
    k_gemm_mfma<<<gb, 256, 0, stream>>>(out1_bf, agg_bf, w2t, b2, outF, nullptr, N);
}